// Round 3
// baseline (10984.492 us; speedup 1.0000x reference)
//
#include <hip/hip_runtime.h>
#include <hip/hip_bf16.h>
#include <cstddef>
#include <cstdint>

#define B     64
#define S     256
#define E     640
#define H     512
#define TSTEPS (S - 1)       // 255
#define ZDIM  4096
#define KT    64
#define HS    (B * H)        // elems per state cell (32768)
#define NBLK  256

typedef __attribute__((ext_vector_type(8)))  __bf16 bf16x8;
typedef __attribute__((ext_vector_type(4)))  float  f32x4;
typedef __attribute__((ext_vector_type(16))) float  f32x16;

__device__ __forceinline__ float sigf(float x) { return 1.0f / (1.0f + __expf(-x)); }
__device__ __forceinline__ float tanhfast(float x) { return 1.0f - 2.0f / (__expf(2.0f * x) + 1.0f); }

__device__ __forceinline__ unsigned short f2bf(float f) {
    union { float f; unsigned u; } x; x.f = f;
    unsigned r = x.u + 0x7fffu + ((x.u >> 16) & 1u);   // RNE
    return (unsigned short)(r >> 16);
}
__device__ __forceinline__ float bf2f(unsigned short u) {
    union { unsigned u; float f; } x; x.u = ((unsigned)u) << 16;
    return x.f;
}

// ---------------------------------------------------------------------------
// Prep kernels
// ---------------------------------------------------------------------------
__global__ __launch_bounds__(256) void conv_x_kernel(
    const float* __restrict__ in, unsigned short* __restrict__ out, int n8)
{
    int i = blockIdx.x * 256 + threadIdx.x;
    if (i >= n8) return;
    const float4* p = (const float4*)(in + (size_t)i * 8);
    float4 a = p[0], b = p[1];
    unsigned short* o = out + (size_t)i * 8;
    o[0] = f2bf(a.x); o[1] = f2bf(a.y); o[2] = f2bf(a.z); o[3] = f2bf(a.w);
    o[4] = f2bf(b.x); o[5] = f2bf(b.y); o[6] = f2bf(b.z); o[7] = f2bf(b.w);
}

// out[d][n][k] = in[d][(n&3)*512 + (n>>2)][k], bf16  (gate-minor packing)
__global__ __launch_bounds__(256) void repack_w_kernel(
    const float* __restrict__ in, unsigned short* __restrict__ out, int K)
{
    int kc = K / 8;
    int i = blockIdx.x * 256 + threadIdx.x;
    if (i >= 2 * 2048 * kc) return;
    int k8 = i % kc;
    int n  = (i / kc) & 2047;
    int d  = i / (kc * 2048);
    int srow = (n & 3) * 512 + (n >> 2);
    const float* src = in + ((size_t)d * 2048 + srow) * K + (size_t)k8 * 8;
    unsigned short* dst = out + ((size_t)d * 2048 + n) * K + (size_t)k8 * 8;
    #pragma unroll
    for (int q = 0; q < 8; ++q) dst[q] = f2bf(src[q]);
}

__global__ __launch_bounds__(256) void pack_bias_kernel(
    const float* __restrict__ bih, const float* __restrict__ bhh, float* __restrict__ out)
{
    int i = blockIdx.x * 256 + threadIdx.x;   // 4096
    if (i >= 4096) return;
    int d = i >> 11, n = i & 2047;
    int s = d * 2048 + (n & 3) * 512 + (n >> 2);
    out[i] = bih[s] + bhh[s];
}

// ---------------------------------------------------------------------------
// Device-scope grid barrier (all NBLK blocks resident: 1 block/CU via LDS)
// ---------------------------------------------------------------------------
__device__ __forceinline__ void grid_barrier(unsigned* cnt, unsigned* gen) {
    __syncthreads();
    if (threadIdx.x == 0) {
        __threadfence();
        unsigned g = __hip_atomic_load(gen, __ATOMIC_RELAXED, __HIP_MEMORY_SCOPE_AGENT);
        unsigned a = __hip_atomic_fetch_add(cnt, 1u, __ATOMIC_ACQ_REL, __HIP_MEMORY_SCOPE_AGENT);
        if (a == NBLK - 1) {
            __hip_atomic_store(cnt, 0u, __ATOMIC_RELAXED, __HIP_MEMORY_SCOPE_AGENT);
            __hip_atomic_fetch_add(gen, 1u, __ATOMIC_RELEASE, __HIP_MEMORY_SCOPE_AGENT);
        } else {
            while (__hip_atomic_load(gen, __ATOMIC_ACQUIRE, __HIP_MEMORY_SCOPE_AGENT) == g) {
                __builtin_amdgcn_s_sleep(2);
            }
        }
        __threadfence();
    }
    __syncthreads();
}

// ---------------------------------------------------------------------------
// Activation + state update for 32x32 D-frag (gate-minor packed cols).
// Owner lane (g == reg&3) activates rows g+8q+4hi of its quad's unit.
// ---------------------------------------------------------------------------
__device__ __forceinline__ void act_update32(
    const f32x16& acc, int n0, int l, int w,
    float* __restrict__ cc, unsigned short* __restrict__ hh)
{
    const int g    = l & 3;
    const int unit = (n0 + (l & 31)) >> 2;
    const int hi   = l >> 5;
    float gi[4], gf[4], gg_[4], go[4];
    #pragma unroll
    for (int r = 0; r < 16; ++r) {
        float v0 = acc[r];
        float v1 = __shfl_xor(v0, 1);
        float v2 = __shfl_xor(v0, 2);
        float v3 = __shfl_xor(v0, 3);
        float pv[4] = {v0, v1, v2, v3};
        const int rg = r & 3;          // owner gate id (compile-time)
        const int q  = r >> 2;
        float iv = pv[rg ^ 0];
        float fv = pv[rg ^ 1];
        float gv = pv[rg ^ 2];
        float ov = pv[rg ^ 3];
        bool own = (g == rg);
        if (own) { gi[q] = iv; gf[q] = fv; gg_[q] = gv; go[q] = ov; }
    }
    #pragma unroll
    for (int q = 0; q < 4; ++q) {
        int row = 32 * w + g + 8 * q + 4 * hi;
        size_t o = (size_t)row * H + unit;
        float cold = cc[o];
        float cnew = sigf(gf[q]) * cold + sigf(gi[q]) * tanhfast(gg_[q]);
        float hnew = sigf(go[q]) * tanhfast(cnew);
        cc[o] = cnew;
        hh[o] = f2bf(hnew);
    }
}

// ---------------------------------------------------------------------------
// Persistent recurrence kernel. 256 blocks x 128 threads, 96KB dynamic LDS.
// bid<128: L0 (d=bit6), else L1. Block tile: 64 batch rows x 32 packed cols.
// Wave w handles rows 32w..32w+31. Weights LDS-resident across all steps.
// ---------------------------------------------------------------------------
__global__ __launch_bounds__(128) void persist_kernel(
    const unsigned short* __restrict__ xb,
    const unsigned short* __restrict__ w0p,
    const unsigned short* __restrict__ wh0p,
    const unsigned short* __restrict__ w1p,
    const unsigned short* __restrict__ wh1p,
    const float* __restrict__ b0p,
    const float* __restrict__ b1p,
    unsigned short* __restrict__ hbuf,   // (2,4,64,512) bf16
    float* __restrict__ cbuf,            // (4,64,512) f32
    unsigned* __restrict__ bar)          // [0]=cnt, [32]=gen
{
    extern __shared__ __align__(16) char lds[];
    const int tid = threadIdx.x;
    const int l   = tid & 63;
    const int w   = tid >> 6;            // 0..1
    const int bid = blockIdx.x;
    const bool isL1 = bid >= 128;
    const int d  = (bid >> 6) & 1;
    const int n0 = (bid & 63) * 32;

    // ---- stage weight slice into LDS (rotate-swizzled, pow2 row strides) ---
    {
        const unsigned short* wih = isL1 ? w1p : w0p;
        const int KX = isL1 ? 1024 : E;                 // 1024 or 640
        const int kc = KX / 8;
        for (int idx = tid; idx < 32 * kc; idx += 128) {
            int r = idx / kc, k8 = idx % kc;
            bf16x8 v = *(const bf16x8*)(wih + ((size_t)d * 2048 + n0 + r) * KX + (size_t)k8 * 8);
            *(bf16x8*)(lds + r * 2048 + ((k8 * 16 + r * 16) & 2047)) = v;
        }
        const unsigned short* whh = isL1 ? wh1p : wh0p;
        for (int idx = tid; idx < 32 * 64; idx += 128) {
            int r = idx / 64, k8 = idx % 64;
            bf16x8 v = *(const bf16x8*)(whh + ((size_t)d * 2048 + n0 + r) * H + (size_t)k8 * 8);
            *(bf16x8*)(lds + 65536 + r * 1024 + ((k8 * 16 + r * 16) & 1023)) = v;
        }
    }
    __syncthreads();

    const float bias = (isL1 ? b1p : b0p)[d * 2048 + n0 + (l & 31)];
    const char* ldsrow_ih = lds + (l & 31) * 2048;
    const char* ldsrow_hh = lds + 65536 + (l & 31) * 1024;
    const int rot  = ((l & 31) * 16) + ((l >> 5) * 16);
    const int arow = 32 * w + (l & 31);
    const int koff = (l >> 5) * 8;

    for (int k = 0; k < TSTEPS + 1; ++k) {
        const int cur = k & 1, nxt = cur ^ 1;
        if (!isL1) {
            if (k <= TSTEPS - 1) {
                f32x16 acc;
                #pragma unroll
                for (int r = 0; r < 16; ++r) acc[r] = bias;
                // x segment (K = 640)
                const unsigned short* Ax = xb + (size_t)k * B * E + (size_t)arow * E + koff;
                #pragma unroll 4
                for (int k0 = 0; k0 < E; k0 += 16) {
                    bf16x8 a = *(const bf16x8*)(Ax + k0);
                    bf16x8 b = *(const bf16x8*)(ldsrow_ih + ((k0 * 2 + rot) & 2047));
                    acc = __builtin_amdgcn_mfma_f32_32x32x16_bf16(a, b, acc, 0, 0, 0);
                }
                // hidden segment (K = 512): h0 cell d, prev step
                const unsigned short* Ah = hbuf + ((size_t)cur * 4 + d) * HS + (size_t)arow * H + koff;
                #pragma unroll 4
                for (int k0 = 0; k0 < H; k0 += 16) {
                    bf16x8 a = *(const bf16x8*)(Ah + k0);
                    bf16x8 b = *(const bf16x8*)(ldsrow_hh + ((k0 * 2 + rot) & 1023));
                    acc = __builtin_amdgcn_mfma_f32_32x32x16_bf16(a, b, acc, 0, 0, 0);
                }
                act_update32(acc, n0, l, w,
                             cbuf + (size_t)d * HS,
                             hbuf + ((size_t)nxt * 4 + d) * HS);
            }
        } else {
            if (k >= 1) {
                f32x16 acc;
                #pragma unroll
                for (int r = 0; r < 16; ++r) acc[r] = bias;
                // input seg A: h0 fwd (cell 0), W k-cols [0,512)
                const unsigned short* A0 = hbuf + ((size_t)cur * 4 + 0) * HS + (size_t)arow * H + koff;
                #pragma unroll 4
                for (int k0 = 0; k0 < H; k0 += 16) {
                    bf16x8 a = *(const bf16x8*)(A0 + k0);
                    bf16x8 b = *(const bf16x8*)(ldsrow_ih + ((k0 * 2 + rot) & 2047));
                    acc = __builtin_amdgcn_mfma_f32_32x32x16_bf16(a, b, acc, 0, 0, 0);
                }
                // input seg B: h0 rev (cell 1), W k-cols [512,1024) -> byte +1024
                const unsigned short* A1 = hbuf + ((size_t)cur * 4 + 1) * HS + (size_t)arow * H + koff;
                #pragma unroll 4
                for (int k0 = 0; k0 < H; k0 += 16) {
                    bf16x8 a = *(const bf16x8*)(A1 + k0);
                    bf16x8 b = *(const bf16x8*)(ldsrow_ih + ((1024 + k0 * 2 + rot) & 2047));
                    acc = __builtin_amdgcn_mfma_f32_32x32x16_bf16(a, b, acc, 0, 0, 0);
                }
                // hidden seg: h1 cell 2+d, prev step
                const unsigned short* A2 = hbuf + ((size_t)cur * 4 + 2 + d) * HS + (size_t)arow * H + koff;
                #pragma unroll 4
                for (int k0 = 0; k0 < H; k0 += 16) {
                    bf16x8 a = *(const bf16x8*)(A2 + k0);
                    bf16x8 b = *(const bf16x8*)(ldsrow_hh + ((k0 * 2 + rot) & 1023));
                    acc = __builtin_amdgcn_mfma_f32_32x32x16_bf16(a, b, acc, 0, 0, 0);
                }
                act_update32(acc, n0, l, w,
                             cbuf + (size_t)(2 + d) * HS,
                             hbuf + ((size_t)nxt * 4 + 2 + d) * HS);
            }
        }
        grid_barrier(bar, bar + 32);
    }
}

// ---------------------------------------------------------------------------
// Head (fp32 VALU). Final h cells 0,1 in hbuf[1]; cells 2,3 in hbuf[0].
// ---------------------------------------------------------------------------
__global__ __launch_bounds__(256) void head_kernel(
    const unsigned short* __restrict__ hbuf,
    const float* __restrict__ cbuf,
    const float* __restrict__ eps,
    const float* __restrict__ Wmu,  const float* __restrict__ bmu,
    const float* __restrict__ Wvar, const float* __restrict__ bvar,
    float* __restrict__ out)
{
    const int tid = threadIdx.x;
    const int b   = tid & 63;
    const int i   = blockIdx.x * 4 + (tid >> 6);

    __shared__ float zs[KT][B + 1];

    float amu = 0.f, alv = 0.f;
    const float* wm = Wmu  + (size_t)i * ZDIM;
    const float* wv = Wvar + (size_t)i * ZDIM;

    for (int k0 = 0; k0 < ZDIM; k0 += KT) {
        __syncthreads();
        for (int idx = tid; idx < (B * KT) / 4; idx += 256) {
            int bb  = idx / (KT / 4);
            int kq4 = (idx % (KT / 4)) * 4;
            int zk  = k0 + kq4;
            int cell = zk >> 10;
            int m    = zk & 1023;
            float4 v;
            if (m < H) {
                const unsigned short* hs = hbuf
                    + (((size_t)((cell < 2) ? 1 : 0)) * 4 + cell) * HS
                    + (size_t)bb * H + m;
                v.x = bf2f(hs[0]); v.y = bf2f(hs[1]); v.z = bf2f(hs[2]); v.w = bf2f(hs[3]);
            } else {
                v = *(const float4*)(cbuf + (size_t)cell * HS + (size_t)bb * H + (m - H));
            }
            zs[kq4 + 0][bb] = v.x; zs[kq4 + 1][bb] = v.y;
            zs[kq4 + 2][bb] = v.z; zs[kq4 + 3][bb] = v.w;
        }
        __syncthreads();
        #pragma unroll
        for (int kk = 0; kk < KT; kk += 4) {
            float4 a = *(const float4*)(wm + k0 + kk);
            float4 c = *(const float4*)(wv + k0 + kk);
            float z0 = zs[kk + 0][b], z1 = zs[kk + 1][b];
            float z2 = zs[kk + 2][b], z3 = zs[kk + 3][b];
            amu += a.x * z0 + a.y * z1 + a.z * z2 + a.w * z3;
            alv += c.x * z0 + c.y * z1 + c.z * z2 + c.w * z3;
        }
    }
    float mu = amu + bmu[i];
    float lv = alv + bvar[i];
    out[(size_t)b * ZDIM + i] = mu + eps[(size_t)b * ZDIM + i] * __expf(0.5f * lv);
}

// ---------------------------------------------------------------------------
extern "C" void kernel_launch(void* const* d_in, const int* in_sizes, int n_in,
                              void* d_out, int out_size, void* d_ws, size_t ws_size,
                              hipStream_t stream) {
    const float* input = (const float*)d_in[0];
    const float* eps   = (const float*)d_in[1];
    const float* w_ih0 = (const float*)d_in[2];
    const float* w_hh0 = (const float*)d_in[3];
    const float* b_ih0 = (const float*)d_in[4];
    const float* b_hh0 = (const float*)d_in[5];
    const float* w_ih1 = (const float*)d_in[6];
    const float* w_hh1 = (const float*)d_in[7];
    const float* b_ih1 = (const float*)d_in[8];
    const float* b_hh1 = (const float*)d_in[9];
    const float* W_mu  = (const float*)d_in[10];
    const float* b_mu  = (const float*)d_in[11];
    const float* W_var = (const float*)d_in[12];
    const float* b_var = (const float*)d_in[13];
    float* out = (float*)d_out;

    uint8_t* base = (uint8_t*)d_ws;
    size_t off = 0;
    auto alloc = [&](size_t bytes) -> void* {
        void* p = base + off;
        off += (bytes + 255) & ~(size_t)255;
        return p;
    };
    unsigned short* xb   = (unsigned short*)alloc((size_t)TSTEPS * B * E * 2);
    unsigned short* w0p  = (unsigned short*)alloc((size_t)2 * 2048 * E * 2);
    unsigned short* wh0p = (unsigned short*)alloc((size_t)2 * 2048 * H * 2);
    unsigned short* w1p  = (unsigned short*)alloc((size_t)2 * 2048 * 1024 * 2);
    unsigned short* wh1p = (unsigned short*)alloc((size_t)2 * 2048 * H * 2);
    float* b0p = (float*)alloc(2 * 2048 * 4);
    float* b1p = (float*)alloc(2 * 2048 * 4);
    unsigned* bar        = (unsigned*)alloc(256);
    unsigned short* hbuf = (unsigned short*)alloc((size_t)2 * 4 * HS * 2);
    float* cbuf          = (float*)alloc((size_t)4 * HS * 4);

    // zero bar + h (both bufs) + c — contiguous region
    hipMemsetAsync(bar, 0, 256 + (size_t)2 * 4 * HS * 2 + (size_t)4 * HS * 4, stream);

    conv_x_kernel<<<(TSTEPS * B * E / 8 + 255) / 256, 256, 0, stream>>>(input, xb, TSTEPS * B * E / 8);
    repack_w_kernel<<<(2 * 2048 * (E / 8) + 255) / 256, 256, 0, stream>>>(w_ih0, w0p, E);
    repack_w_kernel<<<(2 * 2048 * (H / 8) + 255) / 256, 256, 0, stream>>>(w_hh0, wh0p, H);
    repack_w_kernel<<<(2 * 2048 * (1024 / 8) + 255) / 256, 256, 0, stream>>>(w_ih1, w1p, 1024);
    repack_w_kernel<<<(2 * 2048 * (H / 8) + 255) / 256, 256, 0, stream>>>(w_hh1, wh1p, H);
    pack_bias_kernel<<<16, 256, 0, stream>>>(b_ih0, b_hh0, b0p);
    pack_bias_kernel<<<16, 256, 0, stream>>>(b_ih1, b_hh1, b1p);

    const size_t lds_bytes = 96 * 1024;
    hipFuncSetAttribute((const void*)persist_kernel,
                        hipFuncAttributeMaxDynamicSharedMemorySize, (int)lds_bytes);
    persist_kernel<<<NBLK, 128, lds_bytes, stream>>>(
        xb, w0p, wh0p, w1p, wh1p, b0p, b1p, hbuf, cbuf, bar);

    head_kernel<<<ZDIM / 4, 256, 0, stream>>>(hbuf, cbuf, eps, W_mu, b_mu, W_var, b_var, out);
}

// Round 4
// 7855.199 us; speedup vs baseline: 1.3984x; 1.3984x over previous
//
#include <hip/hip_runtime.h>
#include <hip/hip_bf16.h>
#include <cstddef>
#include <cstdint>

#define B     64
#define S     256
#define E     640
#define H     512
#define TSTEPS (S - 1)       // 255
#define ZDIM  4096
#define KT    64
#define HS    (B * H)        // elems per state cell (32768)
#define PBLK  128            // persistent blocks

typedef __attribute__((ext_vector_type(8)))  __bf16 bf16x8;
typedef __attribute__((ext_vector_type(16))) float  f32x16;
typedef unsigned long long ull;

__device__ __forceinline__ float sigf(float x) { return 1.0f / (1.0f + __expf(-x)); }
__device__ __forceinline__ float tanhfast(float x) { return 1.0f - 2.0f / (__expf(2.0f * x) + 1.0f); }

__device__ __forceinline__ unsigned short f2bf(float f) {
    union { float f; unsigned u; } x; x.f = f;
    unsigned r = x.u + 0x7fffu + ((x.u >> 16) & 1u);   // RNE
    return (unsigned short)(r >> 16);
}
__device__ __forceinline__ float bf2f(unsigned short u) {
    union { unsigned u; float f; } x; x.u = ((unsigned)u) << 16;
    return x.f;
}

__device__ __forceinline__ bf16x8 mk8(ull lo, ull hi) {
    union { ulonglong2 u; bf16x8 v; } x;
    x.u.x = lo; x.u.y = hi;
    return x.v;
}

#define HLOAD64(p)     __hip_atomic_load((p), __ATOMIC_RELAXED, __HIP_MEMORY_SCOPE_AGENT)
#define HSTORE64(p, v) __hip_atomic_store((p), (v), __ATOMIC_RELAXED, __HIP_MEMORY_SCOPE_AGENT)

// ---------------------------------------------------------------------------
// Prep kernels
// ---------------------------------------------------------------------------
__global__ __launch_bounds__(256) void conv_x_kernel(
    const float* __restrict__ in, unsigned short* __restrict__ out, int n8)
{
    int i = blockIdx.x * 256 + threadIdx.x;
    if (i >= n8) return;
    const float4* p = (const float4*)(in + (size_t)i * 8);
    float4 a = p[0], b = p[1];
    unsigned short* o = out + (size_t)i * 8;
    o[0] = f2bf(a.x); o[1] = f2bf(a.y); o[2] = f2bf(a.z); o[3] = f2bf(a.w);
    o[4] = f2bf(b.x); o[5] = f2bf(b.y); o[6] = f2bf(b.z); o[7] = f2bf(b.w);
}

// out[d][n][k] = in[d][(n&3)*512 + (n>>2)][k], bf16  (gate-minor packing)
__global__ __launch_bounds__(256) void repack_w_kernel(
    const float* __restrict__ in, unsigned short* __restrict__ out, int K)
{
    int kc = K / 8;
    int i = blockIdx.x * 256 + threadIdx.x;
    if (i >= 2 * 2048 * kc) return;
    int k8 = i % kc;
    int n  = (i / kc) & 2047;
    int d  = i / (kc * 2048);
    int srow = (n & 3) * 512 + (n >> 2);
    const float* src = in + ((size_t)d * 2048 + srow) * K + (size_t)k8 * 8;
    unsigned short* dst = out + ((size_t)d * 2048 + n) * K + (size_t)k8 * 8;
    #pragma unroll
    for (int q = 0; q < 8; ++q) dst[q] = f2bf(src[q]);
}

__global__ __launch_bounds__(256) void pack_bias_kernel(
    const float* __restrict__ bih, const float* __restrict__ bhh, float* __restrict__ out)
{
    int i = blockIdx.x * 256 + threadIdx.x;   // 4096
    if (i >= 4096) return;
    int d = i >> 11, n = i & 2047;
    int s = d * 2048 + (n & 3) * 512 + (n >> 2);
    out[i] = bih[s] + bhh[s];
}

// ---------------------------------------------------------------------------
// Epoch grid barrier: no fences, no acquire; relies on syncthreads vmcnt drain
// + coherent (agent-scope atomic) data accesses.
// ---------------------------------------------------------------------------
__device__ __forceinline__ void grid_barrier(unsigned* cnt, unsigned* gen, unsigned k) {
    __syncthreads();                       // drains vmcnt: h-stores committed at L3
    if (threadIdx.x == 0) {
        unsigned a = __hip_atomic_fetch_add(cnt, 1u, __ATOMIC_RELAXED, __HIP_MEMORY_SCOPE_AGENT);
        if (a == PBLK - 1) {
            __hip_atomic_store(cnt, 0u, __ATOMIC_RELAXED, __HIP_MEMORY_SCOPE_AGENT);
            asm volatile("s_waitcnt vmcnt(0)" ::: "memory");   // cnt reset acked before gen bump
            __hip_atomic_store(gen, k + 1u, __ATOMIC_RELAXED, __HIP_MEMORY_SCOPE_AGENT);
        } else {
            while (__hip_atomic_load(gen, __ATOMIC_RELAXED, __HIP_MEMORY_SCOPE_AGENT) <= k) {}
        }
    }
    asm volatile("" ::: "memory");
    __syncthreads();
}

// ---------------------------------------------------------------------------
// Batched coherent A-loads (h state) + MFMA consumers
// ---------------------------------------------------------------------------
__device__ __forceinline__ void issue8(ull* bf, const ull* hp, int b8) {
#pragma unroll
    for (int j = 0; j < 8; ++j) {
        bf[2*j]   = HLOAD64(hp + (size_t)(b8 + j) * 4);
        bf[2*j+1] = HLOAD64(hp + (size_t)(b8 + j) * 4 + 1);
    }
}

__device__ __forceinline__ void consume8_lds(const ull* bf, int b8,
    const char* ldsrow, int rotofs, int wrapB, f32x16& a0, f32x16& a1)
{
#pragma unroll
    for (int j = 0; j < 8; ++j) {
        bf16x8 a = mk8(bf[2*j], bf[2*j+1]);
        int o = (b8 + j) * 32 + rotofs;
        o -= (o >= wrapB) ? wrapB : 0;
        bf16x8 b = *(const bf16x8*)(ldsrow + o);
        if ((b8 + j) & 1) a1 = __builtin_amdgcn_mfma_f32_32x32x16_bf16(a, b, a1, 0, 0, 0);
        else              a0 = __builtin_amdgcn_mfma_f32_32x32x16_bf16(a, b, a0, 0, 0, 0);
    }
}

__device__ __forceinline__ void consume8_glb(const ull* bf, int b8,
    const unsigned short* wp, f32x16& a0, f32x16& a1)
{
#pragma unroll
    for (int j = 0; j < 8; ++j) {
        bf16x8 a = mk8(bf[2*j], bf[2*j+1]);
        bf16x8 b = *(const bf16x8*)(wp + (size_t)(b8 + j) * 16);
        if ((b8 + j) & 1) a1 = __builtin_amdgcn_mfma_f32_32x32x16_bf16(a, b, a1, 0, 0, 0);
        else              a0 = __builtin_amdgcn_mfma_f32_32x32x16_bf16(a, b, a0, 0, 0, 0);
    }
}

// full K=512 h-cell segment, B from LDS (3-deep rotating load batches)
__device__ __forceinline__ void hcell_lds(const ull* hp, const char* ldsrow,
    int rotofs, int wrapB, f32x16& a0, f32x16& a1)
{
    ull b0[16], b1[16], b2[16];
    issue8(b0, hp, 0); issue8(b1, hp, 8); issue8(b2, hp, 16);
    consume8_lds(b0, 0,  ldsrow, rotofs, wrapB, a0, a1);
    issue8(b0, hp, 24);
    consume8_lds(b1, 8,  ldsrow, rotofs, wrapB, a0, a1);
    consume8_lds(b2, 16, ldsrow, rotofs, wrapB, a0, a1);
    consume8_lds(b0, 24, ldsrow, rotofs, wrapB, a0, a1);
}

// full K=512 h-cell segment, B streamed from global (L2)
__device__ __forceinline__ void hcell_glb(const ull* hp, const unsigned short* wp,
    f32x16& a0, f32x16& a1)
{
    ull b0[16], b1[16], b2[16];
    issue8(b0, hp, 0); issue8(b1, hp, 8); issue8(b2, hp, 16);
    consume8_glb(b0, 0,  wp, a0, a1);
    issue8(b0, hp, 24);
    consume8_glb(b1, 8,  wp, a0, a1);
    consume8_glb(b2, 16, wp, a0, a1);
    consume8_glb(b0, 24, wp, a0, a1);
}

// ---------------------------------------------------------------------------
// Activation + c-in-registers + packed coherent h store
// ---------------------------------------------------------------------------
__device__ __forceinline__ void act_store(
    const f32x16& a0, const f32x16& a1, int unitg, int wm, int l,
    float* creg, ull* hq_cell)
{
    const int g  = l & 3;
    const int hi = l >> 5;
    float gi[4], gf[4], gg[4], go[4];
#pragma unroll
    for (int r = 0; r < 16; ++r) {
        float v0 = a0[r] + a1[r];
        float v1 = __shfl_xor(v0, 1);
        float v2 = __shfl_xor(v0, 2);
        float v3 = __shfl_xor(v0, 3);
        float pv[4] = {v0, v1, v2, v3};
        const int rg = r & 3, q = r >> 2;
        if (g == rg) { gi[q] = pv[rg^0]; gf[q] = pv[rg^1]; gg[q] = pv[rg^2]; go[q] = pv[rg^3]; }
    }
    const int ubase = unitg & ~3;
#pragma unroll
    for (int q = 0; q < 4; ++q) {
        int row = 32*wm + g + 8*q + 4*hi;
        float cold = creg[q];
        float cnew = sigf(gf[q]) * cold + sigf(gi[q]) * tanhfast(gg[q]);
        float hnew = sigf(go[q]) * tanhfast(cnew);
        creg[q] = cnew;
        unsigned m  = f2bf(hnew);
        unsigned o1 = __shfl_xor(m, 4);
        unsigned d0 = (unitg & 1) ? ((m << 16) | o1) : ((o1 << 16) | m);
        unsigned o2 = __shfl_xor(d0, 8);
        ull q64 = (unitg & 2) ? (((ull)d0 << 32) | (ull)o2) : (((ull)o2 << 32) | (ull)d0);
        if ((l & 12) == 0)
            HSTORE64(hq_cell + (size_t)row * 128 + (ubase >> 2), q64);
    }
}

// ---------------------------------------------------------------------------
// Persistent recurrence kernel. 128 blocks x 256 threads, 144KB dynamic LDS.
// bid<64: L0; else L1. Block tile: 64 batch rows x 64 packed cols.
// Wave w: (wm=w&1) row-half, (wn=w>>1) col-half -> 32x32 MFMA tile.
// ---------------------------------------------------------------------------
__global__ __launch_bounds__(256, 1) void persist_kernel(
    const unsigned short* __restrict__ xb,
    const unsigned short* __restrict__ w0p,
    const unsigned short* __restrict__ wh0p,
    const unsigned short* __restrict__ w1p,
    const unsigned short* __restrict__ wh1p,
    const float* __restrict__ b0p,
    const float* __restrict__ b1p,
    unsigned short* __restrict__ hbuf,   // (2,4,64,512) bf16, coherent-accessed
    float* __restrict__ cbuf,            // (4,64,512) f32 (final only)
    unsigned* __restrict__ bar)          // [0]=cnt, [32]=gen
{
    extern __shared__ __align__(16) char lds[];
    const int tid = threadIdx.x;
    const int l   = tid & 63;
    const int w   = tid >> 6;
    const int wm  = w & 1, wn = w >> 1;
    const int bid = blockIdx.x;
    const bool isL1 = bid >= 64;
    const int g2 = bid & 63;
    const int d  = g2 >> 5;
    const int n0 = (g2 & 31) * 64;
    const int lrow  = wn * 32 + (l & 31);    // weight row (output col), local
    const int khalf = l >> 5;
    const int arow  = wm * 32 + (l & 31);    // batch row for A operand
    const int HHOFF = 64 * 1280;             // L0 hh region offset

    // ---- stage weights into LDS (16B-per-row rotate, exact strides) --------
    if (!isL1) {
        for (int idx = tid; idx < 64 * 80; idx += 256) {   // ih: 64 x 640
            int r = idx / 80, k8 = idx % 80;
            bf16x8 v = *(const bf16x8*)(w0p + ((size_t)d*2048 + n0 + r)*640 + (size_t)k8*8);
            int o = k8*16 + r*16; o -= (o >= 1280) ? 1280 : 0;
            *(bf16x8*)(lds + r*1280 + o) = v;
        }
        for (int idx = tid; idx < 64 * 64; idx += 256) {   // hh: 64 x 512
            int r = idx / 64, k8 = idx % 64;
            bf16x8 v = *(const bf16x8*)(wh0p + ((size_t)d*2048 + n0 + r)*512 + (size_t)k8*8);
            int o = k8*16 + r*16; o -= (o >= 1024) ? 1024 : 0;
            *(bf16x8*)(lds + HHOFF + r*1024 + o) = v;
        }
    } else {
        for (int idx = tid; idx < 64 * 128; idx += 256) {  // ih: 64 x 1024
            int r = idx / 128, k8 = idx % 128;
            bf16x8 v = *(const bf16x8*)(w1p + ((size_t)d*2048 + n0 + r)*1024 + (size_t)k8*8);
            int o = k8*16 + r*16; o -= (o >= 2048) ? 2048 : 0;
            *(bf16x8*)(lds + r*2048 + o) = v;
        }
    }
    __syncthreads();

    const int IHB = isL1 ? 2048 : 1280;
    const float bias = (isL1 ? b1p : b0p)[d*2048 + n0 + lrow];
    const char* ldsrow_ih = lds + (size_t)lrow * IHB;
    const char* ldsrow_hh = lds + HHOFF + (size_t)lrow * 1024;
    const int rot = lrow * 16 + khalf * 16;
    const int unitg = ((n0 + lrow) >> 2);
    float creg[4] = {0.f, 0.f, 0.f, 0.f};
    const ull* hb = (const ull*)hbuf;
    ull*       hw = (ull*)hbuf;
    const unsigned short* whh1_lane =
        wh1p + ((size_t)d*2048 + n0 + lrow) * 512 + khalf * 8;

    for (int k = 0; k <= TSTEPS; ++k) {
        const int cur = k & 1, nxt = cur ^ 1;
        const size_t rb = (size_t)cur * 4 * 8192;   // u64 units per buffer
        if (!isL1) {
            if (k < TSTEPS) {
                f32x16 a0, a1;
#pragma unroll
                for (int r = 0; r < 16; ++r) { a0[r] = bias; a1[r] = 0.f; }
                // x segment (K=640), plain loads (L2-hot)
                const unsigned short* Ax = xb + (size_t)k*B*E + (size_t)arow*E + khalf*8;
#pragma unroll 8
                for (int k0 = 0; k0 < E; k0 += 16) {
                    bf16x8 a = *(const bf16x8*)(Ax + k0);
                    int o = k0*2 + rot; o -= (o >= 1280) ? 1280 : 0;
                    bf16x8 b = *(const bf16x8*)(ldsrow_ih + o);
                    if ((k0 >> 4) & 1) a1 = __builtin_amdgcn_mfma_f32_32x32x16_bf16(a, b, a1, 0, 0, 0);
                    else               a0 = __builtin_amdgcn_mfma_f32_32x32x16_bf16(a, b, a0, 0, 0, 0);
                }
                // hidden segment (K=512), coherent A from hbuf[cur] cell d
                const ull* hp = hb + rb + (size_t)d*8192 + (size_t)arow*128 + khalf*2;
                hcell_lds(hp, ldsrow_hh, rot, 1024, a0, a1);
                act_store(a0, a1, unitg, wm, l, creg,
                          hw + (size_t)nxt*4*8192 + (size_t)d*8192);
            }
        } else {
            if (k >= 1) {
                f32x16 a0, a1;
#pragma unroll
                for (int r = 0; r < 16; ++r) { a0[r] = bias; a1[r] = 0.f; }
                const ull* hp0 = hb + rb + (size_t)0*8192 + (size_t)arow*128 + khalf*2;
                hcell_lds(hp0, ldsrow_ih, rot,        2048, a0, a1);
                const ull* hp1 = hb + rb + (size_t)1*8192 + (size_t)arow*128 + khalf*2;
                hcell_lds(hp1, ldsrow_ih, rot + 1024, 2048, a0, a1);
                const ull* hp2 = hb + rb + (size_t)(2+d)*8192 + (size_t)arow*128 + khalf*2;
                hcell_glb(hp2, whh1_lane, a0, a1);
                act_store(a0, a1, unitg, wm, l, creg,
                          hw + (size_t)nxt*4*8192 + (size_t)(2+d)*8192);
            }
        }
        if (k < TSTEPS) grid_barrier(bar, bar + 32, (unsigned)k);
    }

    // final c write-out (plain stores; visible to head after kernel boundary)
    {
        float* cc = cbuf + (size_t)(isL1 ? (2 + d) : d) * HS;
        const int g = l & 3, hi = l >> 5;
#pragma unroll
        for (int q = 0; q < 4; ++q) {
            int row = 32*wm + g + 8*q + 4*hi;
            cc[(size_t)row * 512 + unitg] = creg[q];
        }
    }
}

// ---------------------------------------------------------------------------
// Head (fp32 VALU). Final h cells 0,1 in hbuf[1]; cells 2,3 in hbuf[0].
// ---------------------------------------------------------------------------
__global__ __launch_bounds__(256) void head_kernel(
    const unsigned short* __restrict__ hbuf,
    const float* __restrict__ cbuf,
    const float* __restrict__ eps,
    const float* __restrict__ Wmu,  const float* __restrict__ bmu,
    const float* __restrict__ Wvar, const float* __restrict__ bvar,
    float* __restrict__ out)
{
    const int tid = threadIdx.x;
    const int b   = tid & 63;
    const int i   = blockIdx.x * 4 + (tid >> 6);

    __shared__ float zs[KT][B + 1];

    float amu = 0.f, alv = 0.f;
    const float* wm = Wmu  + (size_t)i * ZDIM;
    const float* wv = Wvar + (size_t)i * ZDIM;

    for (int k0 = 0; k0 < ZDIM; k0 += KT) {
        __syncthreads();
        for (int idx = tid; idx < (B * KT) / 4; idx += 256) {
            int bb  = idx / (KT / 4);
            int kq4 = (idx % (KT / 4)) * 4;
            int zk  = k0 + kq4;
            int cell = zk >> 10;
            int m    = zk & 1023;
            float4 v;
            if (m < H) {
                const unsigned short* hs = hbuf
                    + (((size_t)((cell < 2) ? 1 : 0)) * 4 + cell) * HS
                    + (size_t)bb * H + m;
                v.x = bf2f(hs[0]); v.y = bf2f(hs[1]); v.z = bf2f(hs[2]); v.w = bf2f(hs[3]);
            } else {
                v = *(const float4*)(cbuf + (size_t)cell * HS + (size_t)bb * H + (m - H));
            }
            zs[kq4 + 0][bb] = v.x; zs[kq4 + 1][bb] = v.y;
            zs[kq4 + 2][bb] = v.z; zs[kq4 + 3][bb] = v.w;
        }
        __syncthreads();
        #pragma unroll
        for (int kk = 0; kk < KT; kk += 4) {
            float4 a = *(const float4*)(wm + k0 + kk);
            float4 c = *(const float4*)(wv + k0 + kk);
            float z0 = zs[kk + 0][b], z1 = zs[kk + 1][b];
            float z2 = zs[kk + 2][b], z3 = zs[kk + 3][b];
            amu += a.x * z0 + a.y * z1 + a.z * z2 + a.w * z3;
            alv += c.x * z0 + c.y * z1 + c.z * z2 + c.w * z3;
        }
    }
    float mu = amu + bmu[i];
    float lv = alv + bvar[i];
    out[(size_t)b * ZDIM + i] = mu + eps[(size_t)b * ZDIM + i] * __expf(0.5f * lv);
}

// ---------------------------------------------------------------------------
extern "C" void kernel_launch(void* const* d_in, const int* in_sizes, int n_in,
                              void* d_out, int out_size, void* d_ws, size_t ws_size,
                              hipStream_t stream) {
    const float* input = (const float*)d_in[0];
    const float* eps   = (const float*)d_in[1];
    const float* w_ih0 = (const float*)d_in[2];
    const float* w_hh0 = (const float*)d_in[3];
    const float* b_ih0 = (const float*)d_in[4];
    const float* b_hh0 = (const float*)d_in[5];
    const float* w_ih1 = (const float*)d_in[6];
    const float* w_hh1 = (const float*)d_in[7];
    const float* b_ih1 = (const float*)d_in[8];
    const float* b_hh1 = (const float*)d_in[9];
    const float* W_mu  = (const float*)d_in[10];
    const float* b_mu  = (const float*)d_in[11];
    const float* W_var = (const float*)d_in[12];
    const float* b_var = (const float*)d_in[13];
    float* out = (float*)d_out;

    uint8_t* base = (uint8_t*)d_ws;
    size_t off = 0;
    auto alloc = [&](size_t bytes) -> void* {
        void* p = base + off;
        off += (bytes + 255) & ~(size_t)255;
        return p;
    };
    unsigned short* xb   = (unsigned short*)alloc((size_t)TSTEPS * B * E * 2);
    unsigned short* w0p  = (unsigned short*)alloc((size_t)2 * 2048 * E * 2);
    unsigned short* wh0p = (unsigned short*)alloc((size_t)2 * 2048 * H * 2);
    unsigned short* w1p  = (unsigned short*)alloc((size_t)2 * 2048 * 1024 * 2);
    unsigned short* wh1p = (unsigned short*)alloc((size_t)2 * 2048 * H * 2);
    float* b0p = (float*)alloc(2 * 2048 * 4);
    float* b1p = (float*)alloc(2 * 2048 * 4);
    unsigned* bar        = (unsigned*)alloc(256);
    unsigned short* hbuf = (unsigned short*)alloc((size_t)2 * 4 * HS * 2);
    float* cbuf          = (float*)alloc((size_t)4 * HS * 4);

    // zero bar + h (both bufs) + c — contiguous region
    hipMemsetAsync(bar, 0, 256 + (size_t)2 * 4 * HS * 2 + (size_t)4 * HS * 4, stream);

    conv_x_kernel<<<(TSTEPS * B * E / 8 + 255) / 256, 256, 0, stream>>>(input, xb, TSTEPS * B * E / 8);
    repack_w_kernel<<<(2 * 2048 * (E / 8) + 255) / 256, 256, 0, stream>>>(w_ih0, w0p, E);
    repack_w_kernel<<<(2 * 2048 * (H / 8) + 255) / 256, 256, 0, stream>>>(w_hh0, wh0p, H);
    repack_w_kernel<<<(2 * 2048 * (1024 / 8) + 255) / 256, 256, 0, stream>>>(w_ih1, w1p, 1024);
    repack_w_kernel<<<(2 * 2048 * (H / 8) + 255) / 256, 256, 0, stream>>>(w_hh1, wh1p, H);
    pack_bias_kernel<<<16, 256, 0, stream>>>(b_ih0, b_hh0, b0p);
    pack_bias_kernel<<<16, 256, 0, stream>>>(b_ih1, b_hh1, b1p);

    const size_t lds_bytes = 144 * 1024;
    hipFuncSetAttribute((const void*)persist_kernel,
                        hipFuncAttributeMaxDynamicSharedMemorySize, (int)lds_bytes);
    persist_kernel<<<PBLK, 256, lds_bytes, stream>>>(
        xb, w0p, wh0p, w1p, wh1p, b0p, b1p, hbuf, cbuf, bar);

    head_kernel<<<ZDIM / 4, 256, 0, stream>>>(hbuf, cbuf, eps, W_mu, b_mu, W_var, b_var, out);
}